// Round 8
// baseline (49.556 us; speedup 1.0000x reference)
//
#include <hip/hip_runtime.h>

// Resample1d: out[b,c,h,w] = lerp of input1[b,c,h,:] at x = w + disp[b,h,w],
// zeroed where x outside [0, w-1].
// Shapes: input1 (B,C,H,W) f32, input2 (B,1,H,W) f32, out (B,C,H,W) f32.
//
// R8 = R5 (best: 45.8us) with ONE change: plain stores instead of
// __builtin_nontemporal_store. A/B test of the store path: R6/R7 proved
// bank conflicts are off the critical path (conflicts 4.5M->0.8M, time
// flat/worse); dwordx4 stores matter (R5 45.8 vs R7-scalar 49.0). The NT
// hint is the last untested macro variable: nt may force low-efficiency
// write-through (then this wins) or protect L3 from write-allocate thrash
// (then this loses and we keep NT).

#define B 4
#define C 64
#define H 256
#define W 512
#define WAVES 4          // waves per block
#define CPW 8            // channels per wave
// grid = (B*H, C/(WAVES*CPW)) = (1024, 2); block = 256

typedef float f32x4 __attribute__((ext_vector_type(4)));

__global__ __launch_bounds__(256) void resample1d_kernel(
    const float* __restrict__ in1,   // (B,C,H,W)
    const float* __restrict__ in2,   // (B,1,H,W)
    float* __restrict__ out)         // (B,C,H,W)
{
    __shared__ float rowbuf[WAVES][W];   // 4 x 2KB, wave-private chunks

    const int tid  = threadIdx.x;
    const int wid  = tid >> 6;
    const int lane = tid & 63;

    const int bh = blockIdx.x;          // 0..B*H-1
    const int b  = bh >> 8;             // / H  (H=256)
    const int cbase = blockIdx.y * (WAVES * CPW) + wid * CPW;

    const size_t chan_stride = (size_t)H * W;
    const float* src = in1 + ((size_t)b * C + cbase) * chan_stride + (size_t)(bh & (H - 1)) * W;
    float*       dst = out + ((size_t)b * C + cbase) * chan_stride + (size_t)(bh & (H - 1)) * W;
    const float* disp_row = in2 + (size_t)bh * W;

    // ---- issue first two channels' loads + disp loads up front ----
    f32x4 pre0[2], pre1[2];             // 2-deep prefetch ring (unrolled -> regs)
    pre0[0] = *(const f32x4*)(src + 4 * lane);
    pre1[0] = *(const f32x4*)(src + 256 + 4 * lane);
    pre0[1] = *(const f32x4*)(src + chan_stride + 4 * lane);
    pre1[1] = *(const f32x4*)(src + chan_stride + 256 + 4 * lane);
    f32x4 d4[2];
    d4[0] = *(const f32x4*)(disp_row + 4 * lane);
    d4[1] = *(const f32x4*)(disp_row + 256 + 4 * lane);

    // ---- per-lane pixel params: w = 4*lane + 256*g + j (hoisted over c) ----
    int   i0[2][4];
    float w0[2][4], w1[2][4];
    #pragma unroll
    for (int g = 0; g < 2; ++g) {
        #pragma unroll
        for (int j = 0; j < 4; ++j) {
            int w = 4 * lane + 256 * g + j;
            float x = (float)w + d4[g][j];
            bool valid = (x >= 0.0f) && (x <= (float)(W - 1));
            float x0 = floorf(x);
            float frac = x - x0;
            i0[g][j] = (int)fminf(fmaxf(x0, 0.0f), (float)(W - 1));
            w0[g][j] = valid ? (1.0f - frac) : 0.0f;
            w1[g][j] = valid ? frac : 0.0f;
        }
    }

    float* rb = rowbuf[wid];

    #pragma unroll
    for (int cc = 0; cc < CPW; ++cc) {
        // staged regs -> wave-private LDS (ds_write_b128, conflict-free)
        *(f32x4*)(rb + 4 * lane)       = pre0[cc & 1];
        *(f32x4*)(rb + 256 + 4 * lane) = pre1[cc & 1];
        // refill the ring slot just consumed (keeps 4 loads in flight)
        if (cc + 2 < CPW) {
            const float* s2 = src + (size_t)(cc + 2) * chan_stride;
            pre0[cc & 1] = *(const f32x4*)(s2 + 4 * lane);
            pre1[cc & 1] = *(const f32x4*)(s2 + 256 + 4 * lane);
        }
        // taps from LDS, lerp, two coalesced dwordx4 PLAIN stores
        float* d = dst + (size_t)cc * chan_stride;
        #pragma unroll
        for (int g = 0; g < 2; ++g) {
            f32x4 r;
            #pragma unroll
            for (int j = 0; j < 4; ++j) {
                int a0 = i0[g][j];
                int a1 = min(a0 + 1, W - 1);
                r[j] = w0[g][j] * rb[a0] + w1[g][j] * rb[a1];
            }
            *(f32x4*)(d + 4 * lane + 256 * g) = r;
        }
    }
}

extern "C" void kernel_launch(void* const* d_in, const int* in_sizes, int n_in,
                              void* d_out, int out_size, void* d_ws, size_t ws_size,
                              hipStream_t stream) {
    const float* in1 = (const float*)d_in[0];
    const float* in2 = (const float*)d_in[1];
    float* out = (float*)d_out;

    dim3 grid(B * H, C / (WAVES * CPW)), block(WAVES * 64);
    resample1d_kernel<<<grid, block, 0, stream>>>(in1, in2, out);
}

// Round 9
// 43.481 us; speedup vs baseline: 1.1397x; 1.1397x over previous
//
#include <hip/hip_runtime.h>

// Resample1d: out[b,c,h,w] = lerp of input1[b,c,h,:] at x = w + disp[b,h,w],
// zeroed where x outside [0, W-1].
// Shapes: input1 (B,C,H,W) f32, input2 (B,1,H,W) f32, out (B,C,H,W) f32.
//
// R9 = R5 (best known: 45.8us, NT dwordx4 stores confirmed by R8 A/B) with
// ONE change: CPW 8 -> 4. R5's grid was exactly one residency (8192 waves =
// 32/CU) -> no oversubscription, tail runs at decaying parallelism
// (OccupancyPercent 55%). Halving per-wave work doubles the grid to 16384
// waves (16 blocks/CU queued, 8 resident) -> retiring waves are replaced,
// tail granularity halves, and the 2-deep ring now keeps 50% of each wave's
// traffic in flight.

#define B 4
#define C 64
#define H 256
#define W 512
#define WAVES 4          // waves per block
#define CPW 4            // channels per wave
// grid = (B*H, C/(WAVES*CPW)) = (1024, 4); block = 256

typedef float f32x4 __attribute__((ext_vector_type(4)));

__global__ __launch_bounds__(256) void resample1d_kernel(
    const float* __restrict__ in1,   // (B,C,H,W)
    const float* __restrict__ in2,   // (B,1,H,W)
    float* __restrict__ out)         // (B,C,H,W)
{
    __shared__ float rowbuf[WAVES][W];   // 4 x 2KB, wave-private chunks

    const int tid  = threadIdx.x;
    const int wid  = tid >> 6;
    const int lane = tid & 63;

    const int bh = blockIdx.x;          // 0..B*H-1
    const int b  = bh >> 8;             // / H  (H=256)
    const int cbase = blockIdx.y * (WAVES * CPW) + wid * CPW;

    const size_t chan_stride = (size_t)H * W;
    const float* src = in1 + ((size_t)b * C + cbase) * chan_stride + (size_t)(bh & (H - 1)) * W;
    float*       dst = out + ((size_t)b * C + cbase) * chan_stride + (size_t)(bh & (H - 1)) * W;
    const float* disp_row = in2 + (size_t)bh * W;

    // ---- issue first two channels' loads + disp loads up front ----
    f32x4 pre0[2], pre1[2];             // 2-deep prefetch ring (unrolled -> regs)
    pre0[0] = *(const f32x4*)(src + 4 * lane);
    pre1[0] = *(const f32x4*)(src + 256 + 4 * lane);
    pre0[1] = *(const f32x4*)(src + chan_stride + 4 * lane);
    pre1[1] = *(const f32x4*)(src + chan_stride + 256 + 4 * lane);
    f32x4 d4[2];
    d4[0] = *(const f32x4*)(disp_row + 4 * lane);
    d4[1] = *(const f32x4*)(disp_row + 256 + 4 * lane);

    // ---- per-lane pixel params: w = 4*lane + 256*g + j (hoisted over c) ----
    int   i0[2][4];
    float w0[2][4], w1[2][4];
    #pragma unroll
    for (int g = 0; g < 2; ++g) {
        #pragma unroll
        for (int j = 0; j < 4; ++j) {
            int w = 4 * lane + 256 * g + j;
            float x = (float)w + d4[g][j];
            bool valid = (x >= 0.0f) && (x <= (float)(W - 1));
            float x0 = floorf(x);
            float frac = x - x0;
            i0[g][j] = (int)fminf(fmaxf(x0, 0.0f), (float)(W - 1));
            w0[g][j] = valid ? (1.0f - frac) : 0.0f;
            w1[g][j] = valid ? frac : 0.0f;
        }
    }

    float* rb = rowbuf[wid];

    #pragma unroll
    for (int cc = 0; cc < CPW; ++cc) {
        // staged regs -> wave-private LDS (ds_write_b128, conflict-free)
        *(f32x4*)(rb + 4 * lane)       = pre0[cc & 1];
        *(f32x4*)(rb + 256 + 4 * lane) = pre1[cc & 1];
        // refill the ring slot just consumed (keeps 4 loads in flight)
        if (cc + 2 < CPW) {
            const float* s2 = src + (size_t)(cc + 2) * chan_stride;
            pre0[cc & 1] = *(const f32x4*)(s2 + 4 * lane);
            pre1[cc & 1] = *(const f32x4*)(s2 + 256 + 4 * lane);
        }
        // taps from LDS, lerp, two coalesced dwordx4 NT stores
        float* d = dst + (size_t)cc * chan_stride;
        #pragma unroll
        for (int g = 0; g < 2; ++g) {
            f32x4 r;
            #pragma unroll
            for (int j = 0; j < 4; ++j) {
                int a0 = i0[g][j];
                int a1 = min(a0 + 1, W - 1);
                r[j] = w0[g][j] * rb[a0] + w1[g][j] * rb[a1];
            }
            __builtin_nontemporal_store(r, (f32x4*)(d + 4 * lane + 256 * g));
        }
    }
}

extern "C" void kernel_launch(void* const* d_in, const int* in_sizes, int n_in,
                              void* d_out, int out_size, void* d_ws, size_t ws_size,
                              hipStream_t stream) {
    const float* in1 = (const float*)d_in[0];
    const float* in2 = (const float*)d_in[1];
    float* out = (float*)d_out;

    dim3 grid(B * H, C / (WAVES * CPW)), block(WAVES * 64);
    resample1d_kernel<<<grid, block, 0, stream>>>(in1, in2, out);
}

// Round 10
// 43.217 us; speedup vs baseline: 1.1467x; 1.0061x over previous
//
#include <hip/hip_runtime.h>

// Resample1d: out[b,c,h,w] = lerp of input1[b,c,h,:] at x = w + disp[b,h,w],
// zeroed where x outside [0, W-1].
// Shapes: input1 (B,C,H,W) f32, input2 (B,1,H,W) f32, out (B,C,H,W) f32.
//
// R10 = R9 with ONE change: CPW 4 -> 2 (continue the oversubscription sweep
// that gave 45.8 -> 43.5). 32768 waves = 4x residency. At CPW=2 the 2-deep
// ring covers the wave's ENTIRE input read (both channel rows issued before
// any compute -> one read burst per wave), tail granularity halves again,
// and the refill branch vanishes. NT dwordx4 stores (R8 A/B), 4*lane+j
// mapping (R5/R7 A/B) kept.

#define B 4
#define C 64
#define H 256
#define W 512
#define WAVES 4          // waves per block
#define CPW 2            // channels per wave
// grid = (B*H, C/(WAVES*CPW)) = (1024, 8); block = 256

typedef float f32x4 __attribute__((ext_vector_type(4)));

__global__ __launch_bounds__(256) void resample1d_kernel(
    const float* __restrict__ in1,   // (B,C,H,W)
    const float* __restrict__ in2,   // (B,1,H,W)
    float* __restrict__ out)         // (B,C,H,W)
{
    __shared__ float rowbuf[WAVES][W];   // 4 x 2KB, wave-private chunks

    const int tid  = threadIdx.x;
    const int wid  = tid >> 6;
    const int lane = tid & 63;

    const int bh = blockIdx.x;          // 0..B*H-1
    const int b  = bh >> 8;             // / H  (H=256)
    const int cbase = blockIdx.y * (WAVES * CPW) + wid * CPW;

    const size_t chan_stride = (size_t)H * W;
    const float* src = in1 + ((size_t)b * C + cbase) * chan_stride + (size_t)(bh & (H - 1)) * W;
    float*       dst = out + ((size_t)b * C + cbase) * chan_stride + (size_t)(bh & (H - 1)) * W;
    const float* disp_row = in2 + (size_t)bh * W;

    // ---- issue BOTH channels' loads + disp loads up front (full coverage) ----
    f32x4 pre0[2], pre1[2];
    pre0[0] = *(const f32x4*)(src + 4 * lane);
    pre1[0] = *(const f32x4*)(src + 256 + 4 * lane);
    pre0[1] = *(const f32x4*)(src + chan_stride + 4 * lane);
    pre1[1] = *(const f32x4*)(src + chan_stride + 256 + 4 * lane);
    f32x4 d4[2];
    d4[0] = *(const f32x4*)(disp_row + 4 * lane);
    d4[1] = *(const f32x4*)(disp_row + 256 + 4 * lane);

    // ---- per-lane pixel params: w = 4*lane + 256*g + j (hoisted over c) ----
    int   i0[2][4];
    float w0[2][4], w1[2][4];
    #pragma unroll
    for (int g = 0; g < 2; ++g) {
        #pragma unroll
        for (int j = 0; j < 4; ++j) {
            int w = 4 * lane + 256 * g + j;
            float x = (float)w + d4[g][j];
            bool valid = (x >= 0.0f) && (x <= (float)(W - 1));
            float x0 = floorf(x);
            float frac = x - x0;
            i0[g][j] = (int)fminf(fmaxf(x0, 0.0f), (float)(W - 1));
            w0[g][j] = valid ? (1.0f - frac) : 0.0f;
            w1[g][j] = valid ? frac : 0.0f;
        }
    }

    float* rb = rowbuf[wid];

    #pragma unroll
    for (int cc = 0; cc < CPW; ++cc) {
        // staged regs -> wave-private LDS (ds_write_b128, conflict-free)
        *(f32x4*)(rb + 4 * lane)       = pre0[cc];
        *(f32x4*)(rb + 256 + 4 * lane) = pre1[cc];
        // taps from LDS, lerp, two coalesced dwordx4 NT stores
        float* d = dst + (size_t)cc * chan_stride;
        #pragma unroll
        for (int g = 0; g < 2; ++g) {
            f32x4 r;
            #pragma unroll
            for (int j = 0; j < 4; ++j) {
                int a0 = i0[g][j];
                int a1 = min(a0 + 1, W - 1);
                r[j] = w0[g][j] * rb[a0] + w1[g][j] * rb[a1];
            }
            __builtin_nontemporal_store(r, (f32x4*)(d + 4 * lane + 256 * g));
        }
    }
}

extern "C" void kernel_launch(void* const* d_in, const int* in_sizes, int n_in,
                              void* d_out, int out_size, void* d_ws, size_t ws_size,
                              hipStream_t stream) {
    const float* in1 = (const float*)d_in[0];
    const float* in2 = (const float*)d_in[1];
    float* out = (float*)d_out;

    dim3 grid(B * H, C / (WAVES * CPW)), block(WAVES * 64);
    resample1d_kernel<<<grid, block, 0, stream>>>(in1, in2, out);
}